// Round 15
// baseline (58.353 us; speedup 1.0000x reference)
//
#include <hip/hip_runtime.h>
#include <hip/hip_bf16.h>

#define BT 128   // B*T
#define NN 256   // nodes
#define FF 128   // features
#define HH 4     // heads
#define DD 32    // head dim
#define XK 136   // LDS k-stride (bf16): 272B, 16B-aligned
#define WCS 264  // LDS col-stride (bf16) for whc: 528B
#define L2E 1.4426950408889634f

typedef __attribute__((ext_vector_type(8))) short bf16x8;
typedef __attribute__((ext_vector_type(4))) float f32x4;
typedef unsigned int uint;
typedef unsigned short ushort;

__device__ __forceinline__ float elu1(float x) { return x > 0.f ? x : (__expf(x) - 1.f); }
__device__ __forceinline__ float exp2_fast(float x) {
  float r; asm("v_exp_f32 %0, %1" : "=v"(r) : "v"(x)); return r;
}
__device__ __forceinline__ ushort f2bfn(float f) {
  __hip_bfloat16 h = __float2bfloat16(f);
  return *reinterpret_cast<ushort*>(&h);
}
__device__ __forceinline__ float bf2f(ushort u) {
  union { uint u; float f; } v; v.u = ((uint)u) << 16; return v.f;
}
__device__ __forceinline__ uint pk2(float a, float b) {  // -> v_cvt_pk_bf16_f32
  return (uint)f2bfn(a) | ((uint)f2bfn(b) << 16);
}

// DENSE layer: no compaction. Masked j handled by s2 = -2e9 (p = 0 exactly);
// masked rows computed but dead (LN masks at the end). Everything static:
// 16 row-tiles, 4 j-blocks, full unroll. x/resid loads issue at t=0 (no jmap
// indirection); only 2 barriers. Block = (bt, head), XCD-grouped; 8 waves.
template<bool L0F>
__global__ __launch_bounds__(512)
__attribute__((amdgpu_waves_per_eu(4)))
void layer_kernel(
    const float* __restrict__ xin, const ushort* __restrict__ xprev,
    const int* __restrict__ mask, const float* __restrict__ W,
    const float* __restrict__ av, ushort* __restrict__ xg) {
  __shared__ __align__(16) ushort wt[DD * XK];    // 8.7 KB
  __shared__ __align__(16) ushort whc[DD * WCS];  // 16.9 KB
  __shared__ __align__(16) ushort was[2][FF];     // 0.5 KB: bf16 W@a1, W@a2
  __shared__ __align__(16) float s1s[NN];
  __shared__ __align__(16) float s2c[NN];
  __shared__ int mvs[NN];

  // XCD-grouped decode: b = (bt>>4) + 8*((bt&15) + 16*h)
  const int b = blockIdx.x;
  const int s = b >> 3;
  const int bt = (b & 7) * 16 + (s & 15);
  const int h = s >> 4;
  const int tid = threadIdx.x;
  const int lane = tid & 63;
  const int w = tid >> 6;          // 0..7
  const int la = lane & 15, lg = lane >> 4;

  // ---- t0: issue x A-fragment loads for this wave's 2 row-tiles (w, 8+w) ----
  const int r0 = w * 16 + la;
  const int r1 = 128 + w * 16 + la;
  bf16x8 af0[4], af1[4];
  float4 v0[4][2], v1[4][2];
  if (L0F) {
    const float* xp0 = xin + ((size_t)bt * NN + r0) * FF;
    const float* xp1 = xin + ((size_t)bt * NN + r1) * FF;
    #pragma unroll
    for (int ks = 0; ks < 4; ++ks) {
      v0[ks][0] = *(const float4*)&xp0[ks * 32 + lg * 8];
      v0[ks][1] = *(const float4*)&xp0[ks * 32 + lg * 8 + 4];
      v1[ks][0] = *(const float4*)&xp1[ks * 32 + lg * 8];
      v1[ks][1] = *(const float4*)&xp1[ks * 32 + lg * 8 + 4];
    }
  } else {
    const ushort* xp0 = xprev + ((size_t)bt * NN + r0) * FF;
    const ushort* xp1 = xprev + ((size_t)bt * NN + r1) * FF;
    #pragma unroll
    for (int ks = 0; ks < 4; ++ks) {
      af0[ks] = *(const bf16x8*)&xp0[ks * 32 + lg * 8];
      af1[ks] = *(const bf16x8*)&xp1[ks * 32 + lg * 8];
    }
  }
  // resid prefetch for this wave's PV rows (natural addresses, t0 issue)
  float rpre[2][2][4];
  #pragma unroll
  for (int mi = 0; mi < 2; ++mi) {
    #pragma unroll
    for (int reg = 0; reg < 4; ++reg) {
      const int c2 = (mi * 8 + w) * 16 + lg * 4 + reg;
      #pragma unroll
      for (int nt = 0; nt < 2; ++nt) {
        const int f = h * DD + nt * 16 + la;
        rpre[mi][nt][reg] = L0F ? xin[((size_t)bt * NN + c2) * FF + f]
                                : bf2f(xprev[((size_t)bt * NN + c2) * FF + f]);
      }
    }
  }
  // mask -> LDS (used by score writers after bar1)
  if (tid < NN) mvs[tid] = mask[bt * NN + tid] > 0;

  // ---- W col-slice -> wt; W@a row-dots -> was ----
  {
    const int n = tid & 31;
    const int k0 = (tid >> 5) * 8;
    float wv[8];
    #pragma unroll
    for (int p = 0; p < 8; ++p) wv[p] = W[(k0 + p) * FF + h * DD + n];
    uint4 q;
    q.x = pk2(wv[0], wv[1]); q.y = pk2(wv[2], wv[3]);
    q.z = pk2(wv[4], wv[5]); q.w = pk2(wv[6], wv[7]);
    *(uint4*)&wt[n * XK + k0] = q;
  }
  if (tid < FF) {
    const float* wr = W + (size_t)tid * FF + h * DD;
    float wa1 = 0.f, wa2 = 0.f;
    #pragma unroll
    for (int d4 = 0; d4 < DD; d4 += 4) {
      float4 wq = *(const float4*)&wr[d4];
      float4 q1 = *(const float4*)&av[d4];
      float4 q2 = *(const float4*)&av[DD + d4];
      wa1 = fmaf(wq.x, q1.x, fmaf(wq.y, q1.y, fmaf(wq.z, q1.z, fmaf(wq.w, q1.w, wa1))));
      wa2 = fmaf(wq.x, q2.x, fmaf(wq.y, q2.y, fmaf(wq.z, q2.z, fmaf(wq.w, q2.w, wa2))));
    }
    was[0][tid] = f2bfn(wa1);
    was[1][tid] = f2bfn(wa2);
  }
  // cvt x fp32 -> bf16 fragments (L0; frees the float4 staging regs)
  if (L0F) {
    #pragma unroll
    for (int ks = 0; ks < 4; ++ks) {
      union { uint4 q; bf16x8 v; } u;
      u.q.x = pk2(v0[ks][0].x, v0[ks][0].y); u.q.y = pk2(v0[ks][0].z, v0[ks][0].w);
      u.q.z = pk2(v0[ks][1].x, v0[ks][1].y); u.q.w = pk2(v0[ks][1].z, v0[ks][1].w);
      af0[ks] = u.v;
      u.q.x = pk2(v1[ks][0].x, v1[ks][0].y); u.q.y = pk2(v1[ks][0].z, v1[ks][0].w);
      u.q.z = pk2(v1[ks][1].x, v1[ks][1].y); u.q.w = pk2(v1[ks][1].z, v1[ks][1].w);
      af1[ks] = u.v;
    }
  }
  __syncthreads();  // #1: wt, was, mvs ready

  // B fragments: 2 feature tiles + score tile (col0=wa1, col1=wa2, rest 0)
  bf16x8 bfr[2][4], bsc[4];
  #pragma unroll
  for (int ct = 0; ct < 2; ++ct)
    #pragma unroll
    for (int ks = 0; ks < 4; ++ks)
      bfr[ct][ks] = *(const bf16x8*)&wt[(ct * 16 + la) * XK + ks * 32 + lg * 8];
  #pragma unroll
  for (int ks = 0; ks < 4; ++ks) {
    bf16x8 z = {0, 0, 0, 0, 0, 0, 0, 0};
    bsc[ks] = (la < 2) ? *(const bf16x8*)&was[la][ks * 32 + lg * 8] : z;
  }

  // ---- GEMM: 2 static tiles per wave (rt = w, 8+w); 3 accumulators each ----
  #pragma unroll
  for (int mi = 0; mi < 2; ++mi) {
    const int rt = mi * 8 + w;
    f32x4 acc0 = {}, acc1 = {}, accs = {};
    #pragma unroll
    for (int ks = 0; ks < 4; ++ks) {
      const bf16x8 af = mi ? af1[ks] : af0[ks];
      acc0 = __builtin_amdgcn_mfma_f32_16x16x32_bf16(af, bfr[0][ks], acc0, 0, 0, 0);
      acc1 = __builtin_amdgcn_mfma_f32_16x16x32_bf16(af, bfr[1][ks], acc1, 0, 0, 0);
      accs = __builtin_amdgcn_mfma_f32_16x16x32_bf16(af, bsc[ks], accs, 0, 0, 0);
    }
    uint2 pa, pb;
    pa.x = pk2(acc0[0], acc0[1]); pa.y = pk2(acc0[2], acc0[3]);
    pb.x = pk2(acc1[0], acc1[1]); pb.y = pk2(acc1[2], acc1[3]);
    *(uint2*)&whc[la * WCS + rt * 16 + lg * 4] = pa;
    *(uint2*)&whc[(16 + la) * WCS + rt * 16 + lg * 4] = pb;
    if (la < 2) {  // D col0 = s1, col1 = s2; rows = nodes lg*4+reg
      #pragma unroll
      for (int reg = 0; reg < 4; ++reg) {
        const int c = rt * 16 + lg * 4 + reg;
        const float v = accs[reg] * L2E;
        if (la == 0) s1s[c] = v;
        else         s2c[c] = mvs[c] ? v : -2e9f;  // masked j -> p = 0 exactly
      }
    }
  }
  __syncthreads();  // #2: whc, s1s, s2c complete

  // ---- s2max: per-wave reduce over all 256 entries ----
  float m = fmaxf(fmaxf(s2c[lane], s2c[64 + lane]),
                  fmaxf(s2c[128 + lane], s2c[192 + lane]));
  #pragma unroll
  for (int off = 32; off > 0; off >>= 1) m = fmaxf(m, __shfl_xor(m, off));
  const float s2max = m;

  // ---- PV: 2 static tiles per wave; P generated in registers; 4 j-blocks ----
  float s1r[2], em[2];
  #pragma unroll
  for (int mi = 0; mi < 2; ++mi) {
    const float s1v = s1s[(mi * 8 + w) * 16 + la];
    s1r[mi] = s1v;
    const float t = s1v + s2max;
    em[mi] = fmaxf(t, 0.2f * t);  // exact row max (lrelu monotone)
  }
  f32x4 acc[2][2] = {};
  float den[2] = {0.f, 0.f};
  #pragma unroll
  for (int jb = 0; jb < 4; ++jb) {
    #pragma unroll
    for (int ks = 0; ks < 2; ++ks) {
      const int j0 = jb * 64 + ks * 32 + lg * 8;
      float4 sa = *(const float4*)&s2c[j0];
      float4 sb = *(const float4*)&s2c[j0 + 4];
      bf16x8 b0 = *(const bf16x8*)&whc[la * WCS + j0];
      bf16x8 b1 = *(const bf16x8*)&whc[(16 + la) * WCS + j0];
      #pragma unroll
      for (int mi = 0; mi < 2; ++mi) {
        const float s1v = s1r[mi], emv = em[mi];
        float t0 = s1v + sa.x, t1 = s1v + sa.y, t2 = s1v + sa.z, t3 = s1v + sa.w;
        float t4 = s1v + sb.x, t5 = s1v + sb.y, t6 = s1v + sb.z, t7 = s1v + sb.w;
        float p0 = exp2_fast(fmaxf(t0, 0.2f * t0) - emv);
        float p1 = exp2_fast(fmaxf(t1, 0.2f * t1) - emv);
        float p2 = exp2_fast(fmaxf(t2, 0.2f * t2) - emv);
        float p3 = exp2_fast(fmaxf(t3, 0.2f * t3) - emv);
        float p4 = exp2_fast(fmaxf(t4, 0.2f * t4) - emv);
        float p5 = exp2_fast(fmaxf(t5, 0.2f * t5) - emv);
        float p6 = exp2_fast(fmaxf(t6, 0.2f * t6) - emv);
        float p7 = exp2_fast(fmaxf(t7, 0.2f * t7) - emv);
        den[mi] += ((p0 + p1) + (p2 + p3)) + ((p4 + p5) + (p6 + p7));
        union { uint4 q; bf16x8 v; } u;
        u.q.x = pk2(p0, p1); u.q.y = pk2(p2, p3);
        u.q.z = pk2(p4, p5); u.q.w = pk2(p6, p7);
        acc[mi][0] = __builtin_amdgcn_mfma_f32_16x16x32_bf16(u.v, b0, acc[mi][0], 0, 0, 0);
        acc[mi][1] = __builtin_amdgcn_mfma_f32_16x16x32_bf16(u.v, b1, acc[mi][1], 0, 0, 0);
      }
    }
  }
  #pragma unroll
  for (int mi = 0; mi < 2; ++mi) {
    den[mi] += __shfl_xor(den[mi], 16);
    den[mi] += __shfl_xor(den[mi], 32);
  }

  // ---- epilogue: residual (prefetched) + ELU -> dense bf16 xg ----
  #pragma unroll
  for (int mi = 0; mi < 2; ++mi) {
    const float inv = 1.f / den[mi];  // >= 1/256, finite even if all-masked
    #pragma unroll
    for (int reg = 0; reg < 4; ++reg) {
      const float invr = __shfl(inv, lg * 4 + reg);
      const int c2 = (mi * 8 + w) * 16 + lg * 4 + reg;
      #pragma unroll
      for (int nt = 0; nt < 2; ++nt) {
        const int f = h * DD + nt * 16 + la;
        float v = elu1(rpre[mi][nt][reg] + acc[mi][nt][reg] * invr);
        xg[((size_t)bt * NN + c2) * FF + f] = f2bfn(v);
      }
    }
  }
}

// Dense LN: mask read directly; masked rows -> zeros. XCD-grouped decode.
__global__ __launch_bounds__(256) void ln_scatter(
    const ushort* __restrict__ xg1, const int* __restrict__ mask,
    const float* __restrict__ gam, const float* __restrict__ bet,
    float* __restrict__ out) {
  const int b = blockIdx.x;
  const int bt = (b & 7) * 16 + ((b >> 3) & 15);
  const int q = b >> 7;
  const int node = q * 64 + (threadIdx.x >> 2);
  const int fb = (threadIdx.x & 3) * 32;
  const int mv = mask[bt * NN + node] > 0;
  float* op = out + ((size_t)bt * NN + node) * FF + fb;
  if (!mv) {
    float4 z = {0.f, 0.f, 0.f, 0.f};
    #pragma unroll
    for (int i = 0; i < 8; ++i) *(float4*)&op[i * 4] = z;
  } else {
    const ushort* xr = xg1 + ((size_t)bt * NN + node) * FF + fb;
    float f[32];
    #pragma unroll
    for (int i = 0; i < 4; ++i) {
      uint4 u = *(const uint4*)&xr[i * 8];
      const uint* pu = (const uint*)&u;
      #pragma unroll
      for (int e = 0; e < 4; ++e) {
        f[i * 8 + e * 2]     = bf2f((ushort)(pu[e] & 0xffffu));
        f[i * 8 + e * 2 + 1] = bf2f((ushort)(pu[e] >> 16));
      }
    }
    float sum = 0.f, sq = 0.f;
    #pragma unroll
    for (int i = 0; i < 32; ++i) { sum += f[i]; sq = fmaf(f[i], f[i], sq); }
    sum += __shfl_xor(sum, 1); sq += __shfl_xor(sq, 1);
    sum += __shfl_xor(sum, 2); sq += __shfl_xor(sq, 2);
    const float mu = sum * (1.f / FF);
    const float var = sq * (1.f / FF) - mu * mu;
    const float rstd = rsqrtf(var + 1e-5f);
    #pragma unroll
    for (int i = 0; i < 8; ++i) {
      float4 g = *(const float4*)&gam[fb + i * 4];
      float4 bb = *(const float4*)&bet[fb + i * 4];
      float4 o;
      o.x = (f[i * 4]     - mu) * rstd * g.x + bb.x;
      o.y = (f[i * 4 + 1] - mu) * rstd * g.y + bb.y;
      o.z = (f[i * 4 + 2] - mu) * rstd * g.z + bb.z;
      o.w = (f[i * 4 + 3] - mu) * rstd * g.w + bb.w;
      *(float4*)&op[i * 4] = o;
    }
  }
}

extern "C" void kernel_launch(void* const* d_in, const int* in_sizes, int n_in,
                              void* d_out, int out_size, void* d_ws, size_t ws_size,
                              hipStream_t stream) {
  const float* xin   = (const float*)d_in[0];
  const int*   mask  = (const int*)d_in[1];
  const float* W0    = (const float*)d_in[2];
  const float* a0    = (const float*)d_in[3];
  const float* W1    = (const float*)d_in[4];
  const float* a1    = (const float*)d_in[5];
  const float* gamma = (const float*)d_in[6];
  const float* beta  = (const float*)d_in[7];

  ushort* xg0 = (ushort*)d_ws;                   // 8.39 MB dense bf16
  ushort* xg1 = xg0 + (size_t)BT * NN * FF;      // 8.39 MB dense bf16

  layer_kernel<true><<<BT * HH, 512, 0, stream>>>(xin, nullptr, mask, W0, a0, xg0);
  layer_kernel<false><<<BT * HH, 512, 0, stream>>>(nullptr, xg0, mask, W1, a1, xg1);
  ln_scatter<<<BT * 4, 256, 0, stream>>>(xg1, mask, gamma, beta, (float*)d_out);
}